// Round 8
// baseline (1248.663 us; speedup 1.0000x reference)
//
#include <hip/hip_runtime.h>
#include <hip/hip_fp16.h>

// CLDice loss, round 8: round-7 (fp16 state, all fields/batches in one grid)
// restructured to ONE barrier per z-step.
// Identity: with a_k = erode^k(img):
//   skel=0; for k=0..10: delta = relu(a_k - dilate(erode(a_k))); skel += delta*(1-skel)
// Per step s (zi = z0-2+s):
//   phase A: s1(zi-1) from PREVIOUS img buffer -> z-ring -> write b(zi-2) to b[s&1];
//            read ic(zi-1); prefetch skel/weights for zo=zi-3 from global.
//   phase B: store prefetched img(zi) into img[s&1]; prefetch img(zi+1).
//   __syncthreads()   (the only barrier)
//   phase C: dilate b(zi-2) from b[s&1]; z-rings emit output at zo=zi-3.
// img and b double-buffered; every hazard crosses exactly one barrier.
// MODE 0: k=0 (a0 built inline), MODE 1: mid, MODE 2: last (k=10, reduce).
// Workspace: [sums:16 f32][A][B][SK], each 4*VOL fp16 (~56.6 MB) => ~170 MB.

#define ZD 192
#define YD 192
#define XD 192
constexpr int PLANE = YD * XD;
constexpr int VOL   = ZD * PLANE;
constexpr int NVOL4 = 4 * VOL;

constexpr int XT = 64, YT = 16, ZCH = 16;
constexpr int IWQ = 18, SIW = 19;        // img real quads / padded LDS stride (quads)
constexpr int IH  = 20;                  // rows y0-2..y0+17
constexpr int NIMGQ = IH * IWQ;          // 360
constexpr int BWQ = 17, BH = 18;         // b plane: origin x0-1, rows y0-1..y0+16
constexpr int NBQ  = BH * BWQ;           // 306
constexpr int STEPS = ZCH + 5;           // 21
#define PINF __builtin_inff()

__device__ __forceinline__ float4 vf4(float v) { return make_float4(v, v, v, v); }
__device__ __forceinline__ float4 vmin(float4 a, float4 b) {
    return make_float4(fminf(a.x, b.x), fminf(a.y, b.y), fminf(a.z, b.z), fminf(a.w, b.w));
}
__device__ __forceinline__ float4 vmax(float4 a, float4 b) {
    return make_float4(fmaxf(a.x, b.x), fmaxf(a.y, b.y), fmaxf(a.z, b.z), fmaxf(a.w, b.w));
}
__device__ __forceinline__ float4 ldh4(const __half* p) {
    const __half2* q = (const __half2*)p;
    const float2 lo = __half22float2(q[0]);
    const float2 hi = __half22float2(q[1]);
    return make_float4(lo.x, lo.y, hi.x, hi.y);
}
__device__ __forceinline__ void sth4(__half* p, float4 v) {
    __half2* q = (__half2*)p;
    q[0] = __floats2half2_rn(v.x, v.y);
    q[1] = __floats2half2_rn(v.z, v.w);
}

template <int MODE>   // 0=k0, 1=mid, 2=last
__global__ __launch_bounds__(256)
void fused_kernel(const __half* __restrict__ a_in,
                  __half* __restrict__ a_out,
                  __half* __restrict__ skel,
                  const float* __restrict__ logits,
                  const int* __restrict__ targets,
                  float* __restrict__ sums)
{
    __shared__ float simg[2][IH * SIW * 4];
    __shared__ float sbp[2][NBQ * 4 + 8];
    __shared__ float red[4][2];

    const int tx = threadIdx.x, ty = threadIdx.y;   // (16,16)
    const int tid = ty * 16 + tx;
    const int x0 = (blockIdx.x % 3) * XT, y0 = (blockIdx.x / 3) * YT;
    const int z0 = blockIdx.y * ZCH;
    const int zf = blockIdx.z;                      // 0..3
    const int bb = zf & 1, field = zf >> 1;
    const size_t voff = (size_t)zf * VOL;
    const __half* inb  = a_in  + voff;
    __half*       outb = a_out + voff;
    __half*       skb  = skel  + voff;
    const float* lg0 = logits + (size_t)(bb * 2) * VOL;
    const float* lg1 = lg0 + VOL;
    const int*   tgb = targets + (size_t)bb * VOL;

    const int q1off = ((tid & 3) << 6) + (tid >> 2);  // balanced 2nd-chunk id

    // ---- img chunks: qi -> row r=qi/18, col c=qi%18; LDS addr (r*SIW+c)*4
    int im_qi[2] = { tid, 256 + q1off };
    int im_addr[2], im_goff[2]; bool im_ok[2], im_has[2];
    #pragma unroll
    for (int j = 0; j < 2; ++j) {
        const int qi = im_qi[j];
        const int r = qi / IWQ, c = qi - r * IWQ;
        const int gy = y0 - 2 + r, gxb = x0 - 4 + 4 * c;
        im_has[j] = (qi < NIMGQ);
        im_ok[j]  = im_has[j] && gy >= 0 && gy < YD && gxb >= 0 && gxb < XD;
        im_goff[j] = gy * XD + gxb;
        im_addr[j] = (r * SIW + c) * 4;
    }
    // ---- b chunks: qi -> (r=qi/17, c=qi%17); covers (y0-1+r, x0-1+4c)
    int bqi[2], brow[2], bcol[2]; bool bhas[2]; float4 bmask[2];
    #pragma unroll
    for (int j = 0; j < 2; ++j) {
        const int qi = (j == 0) ? tid : 256 + q1off;
        bqi[j] = qi;
        bhas[j] = (qi < NBQ);
        const int r = qi / BWQ, c = qi - r * BWQ;
        brow[j] = r; bcol[j] = c;
        const int gy = y0 - 1 + r, gxb = x0 - 1 + 4 * c;
        const bool yv = (gy >= 0 && gy < YD);
        float4 m;
        m.x = (yv && gxb     >= 0 && gxb     < XD) ? PINF : -PINF;
        m.y = (yv && gxb + 1 >= 0 && gxb + 1 < XD) ? PINF : -PINF;
        m.z = (yv && gxb + 2 >= 0 && gxb + 2 < XD) ? PINF : -PINF;
        m.w = (yv && gxb + 3 >= 0 && gxb + 3 < XD) ? PINF : -PINF;
        bmask[j] = m;
    }

    auto loadq = [&](int zi, int j) -> float4 {
        if (zi < 0 || zi >= ZD || !im_ok[j]) return vf4(PINF);
        const size_t p = (size_t)zi * PLANE + im_goff[j];
        if constexpr (MODE == 0) {
            if (field) {
                const int4 t = *(const int4*)(tgb + p);
                return make_float4(t.x == 1 ? 1.f : 0.f, t.y == 1 ? 1.f : 0.f,
                                   t.z == 1 ? 1.f : 0.f, t.w == 1 ? 1.f : 0.f);
            } else {
                const float4 a = *(const float4*)(lg0 + p);
                const float4 b = *(const float4*)(lg1 + p);
                return make_float4(1.f / (1.f + __expf(a.x - b.x)),
                                   1.f / (1.f + __expf(a.y - b.y)),
                                   1.f / (1.f + __expf(a.z - b.z)),
                                   1.f / (1.f + __expf(a.w - b.w)));
            }
        } else {
            return ldh4(inb + p);
        }
    };

    // erode xy-min for b slot j from img plane sp
    auto s1_of = [&](const float* sp, int j) -> float4 {
        const float* p = sp + brow[j] * (SIW * 4) + 4 * bcol[j];
        const float4 A0 = *(const float4*)p;
        const float4 B0 = *(const float4*)(p + 4);
        const float4 A1 = *(const float4*)(p + SIW * 4);
        const float4 B1 = *(const float4*)(p + SIW * 4 + 4);
        const float4 A2 = *(const float4*)(p + SIW * 8);
        const float4 B2 = *(const float4*)(p + SIW * 8 + 4);
        const float az = fminf(A0.z, fminf(A1.z, A2.z));
        const float aw = fminf(A0.w, fminf(A1.w, A2.w));
        const float4 Br = vmin(B0, vmin(B1, B2));
        const float t1 = fminf(aw, Br.x);
        const float t2 = fminf(Br.y, Br.z);
        return make_float4(fminf(az, t1), fminf(t1, Br.y),
                           fminf(Br.x, t2), fminf(t2, Br.w));
    };

    float4 p2a = vf4(PINF), p1a = vf4(PINF);   // s1 z-ring chunk0
    float4 p2b = vf4(PINF), p1b = vf4(PINF);   // s1 z-ring chunk1
    float4 s2p1 = vf4(-PINF), s2p2 = vf4(-PINF);
    float4 icp1 = vf4(0.f), icp2 = vf4(0.f), bcp1 = vf4(0.f);
    float sd = 0.f, ss = 0.f;

    float4 ca0 = loadq(z0 - 2, 0);
    float4 ca1 = loadq(z0 - 2, 1);

    #pragma unroll 2
    for (int s = 0; s < STEPS; ++s) {
        const int zi = z0 - 2 + s;
        const int zo = zi - 3;
        // ---- output-plane global prefetches (independent of LDS)
        size_t oidx = 0;
        float4 sk4 = vf4(0.f), w4 = vf4(0.f);
        const bool emit = (s >= 5);
        if (emit) {
            oidx = (size_t)zo * PLANE + (size_t)(y0 + ty) * XD + (x0 + 4 * tx);
            if constexpr (MODE != 0) sk4 = ldh4(skb + oidx);
            if constexpr (MODE == 2) {
                if (field) {
                    const float4 a = *(const float4*)(lg0 + oidx);
                    const float4 b = *(const float4*)(lg1 + oidx);
                    w4 = make_float4(1.f / (1.f + __expf(a.x - b.x)),
                                     1.f / (1.f + __expf(a.y - b.y)),
                                     1.f / (1.f + __expf(a.z - b.z)),
                                     1.f / (1.f + __expf(a.w - b.w)));
                } else {
                    const int4 t = *(const int4*)(tgb + oidx);
                    w4 = make_float4(t.x == 1 ? 1.f : 0.f, t.y == 1 ? 1.f : 0.f,
                                     t.z == 1 ? 1.f : 0.f, t.w == 1 ? 1.f : 0.f);
                }
            }
        }
        // ---- phase A: s1(zi-1) from previous img buffer; write b(zi-2) to b[s&1]
        float4 icq = vf4(0.f);
        if (s >= 1) {
            const float* spv = simg[(s + 1) & 1];
            float* bw = sbp[s & 1];
            {
                const float4 cur = s1_of(spv, 0);
                const float4 b = vmin(vmin(p2a, p1a), cur);
                *(float4*)(bw + 4 * bqi[0]) = vmin(b, bmask[0]);
                p2a = p1a; p1a = cur;
            }
            if (bhas[1]) {
                const float4 cur = s1_of(spv, 1);
                const float4 b = vmin(vmin(p2b, p1b), cur);
                *(float4*)(bw + 4 * bqi[1]) = vmin(b, bmask[1]);
                p2b = p1b; p1b = cur;
            }
            icq = *(const float4*)(spv + ((ty + 2) * SIW + tx + 1) * 4);
        }
        // ---- phase B: stage img(zi); prefetch img(zi+1)
        if (s < STEPS - 1) {
            float* sp = simg[s & 1];
            *(float4*)(sp + im_addr[0]) = ca0;
            if (im_has[1]) *(float4*)(sp + im_addr[1]) = ca1;
            if (s + 1 < STEPS - 1) { ca0 = loadq(zi + 1, 0); ca1 = loadq(zi + 1, 1); }
        }
        __syncthreads();                        // the only barrier
        // ---- phase C: dilate b(zi-2) from b[s&1]
        const int zb = zi - 2;
        const bool zbv = (s >= 3) && (zb >= 0) && (zb < ZD);
        float4 s2n = vf4(-PINF), bcq = vf4(0.f);
        if (zbv) {
            const float* p = sbp[s & 1] + (ty * BWQ + tx) * 4;
            const float4 U0 = *(const float4*)p;
            const float4 V0 = *(const float4*)(p + 4);
            const float4 U1 = *(const float4*)(p + BWQ * 4);
            const float4 V1 = *(const float4*)(p + BWQ * 4 + 4);
            const float4 U2 = *(const float4*)(p + BWQ * 8);
            const float4 V2 = *(const float4*)(p + BWQ * 8 + 4);
            bcq = make_float4(U1.y, U1.z, U1.w, V1.x);     // b at the output quad
            const float4 Ur = vmax(U0, vmax(U1, U2));
            const float vx = fmaxf(V0.x, fmaxf(V1.x, V2.x));
            const float vy = fmaxf(V0.y, fmaxf(V1.y, V2.y));
            const float t1 = fmaxf(Ur.y, Ur.z);
            const float t2 = fmaxf(Ur.w, vx);
            s2n.x = fmaxf(Ur.x, t1);
            s2n.y = fmaxf(t1, Ur.w);
            s2n.z = fmaxf(Ur.z, t2);
            s2n.w = fmaxf(t2, vy);
        }
        // ---- emit zo = zi-3
        if (emit) {
            const float4 d = vmax(s2p2, vmax(s2p1, s2n));
            float4 dl;
            dl.x = fmaxf(icp2.x - d.x, 0.f);
            dl.y = fmaxf(icp2.y - d.y, 0.f);
            dl.z = fmaxf(icp2.z - d.z, 0.f);
            dl.w = fmaxf(icp2.w - d.w, 0.f);
            if constexpr (MODE == 0) {
                sth4(skb + oidx, dl);             // skel = delta0
                sth4(outb + oidx, bcp1);          // a1
            } else {
                float4 sv;
                sv.x = sk4.x + dl.x * (1.f - sk4.x);
                sv.y = sk4.y + dl.y * (1.f - sk4.y);
                sv.z = sk4.z + dl.z * (1.f - sk4.z);
                sv.w = sk4.w + dl.w * (1.f - sk4.w);
                if constexpr (MODE == 1) {
                    sth4(skb + oidx, sv);
                    sth4(outb + oidx, bcp1);      // a_{k+1}
                } else {
                    sd += sv.x * w4.x + sv.y * w4.y + sv.z * w4.z + sv.w * w4.w;
                    ss += sv.x + sv.y + sv.z + sv.w;
                }
            }
        }
        s2p2 = s2p1; s2p1 = s2n;
        icp2 = icp1; icp1 = icq;
        bcp1 = bcq;
    }

    if constexpr (MODE == 2) {
        #pragma unroll
        for (int o = 32; o; o >>= 1) {
            sd += __shfl_down(sd, o, 64);
            ss += __shfl_down(ss, o, 64);
        }
        const int w = tid >> 6;
        if ((tid & 63) == 0) { red[w][0] = sd; red[w][1] = ss; }
        __syncthreads();
        if (tid == 0) {
            float a = 0.f, b = 0.f;
            #pragma unroll
            for (int i = 0; i < 4; ++i) { a += red[i][0]; b += red[i][1]; }
            atomicAdd(&sums[2 * field + 0], a);
            atomicAdd(&sums[2 * field + 1], b);
        }
    }
}

__global__ void final_kernel(const float* __restrict__ sums, float* __restrict__ out)
{
    float tprec = (sums[0] + 1.f) / (sums[1] + 1.f);
    float tsens = (sums[2] + 1.f) / (sums[3] + 1.f);
    float cl = 2.f * tprec * tsens / (tprec + tsens + 1e-7f);
    out[0] = 1.f - cl;
}

extern "C" void kernel_launch(void* const* d_in, const int* in_sizes, int n_in,
                              void* d_out, int out_size, void* d_ws, size_t ws_size,
                              hipStream_t stream)
{
    const float* logits  = (const float*)d_in[0];
    const int*   targets = (const int*)d_in[1];
    float* out  = (float*)d_out;

    float*  sums = (float*)d_ws;
    __half* A    = (__half*)(sums + 16);
    __half* B    = A + NVOL4;
    __half* SK   = B + NVOL4;
    __half* bufs[2] = { A, B };

    hipMemsetAsync(sums, 0, 16 * sizeof(float), stream);

    dim3 g(3 * (YD / YT), ZD / ZCH, 4);    // (36, 12, 4) = 1728 blocks
    dim3 blk(16, 16, 1);

    // k = 0: build a0 inline, skel = delta0, write a1 -> A
    fused_kernel<0><<<g, blk, 0, stream>>>(A, A, SK, logits, targets, sums);
    // k = 1..9: a_k -> a_{k+1}, update skel
    for (int k = 1; k <= 9; ++k) {
        const __half* cin = bufs[(k + 1) & 1];
        __half*       cout = bufs[k & 1];
        fused_kernel<1><<<g, blk, 0, stream>>>(cin, cout, SK, logits, targets, sums);
    }
    // k = 10: read a10 (in B), reduce
    fused_kernel<2><<<g, blk, 0, stream>>>(bufs[1], A, SK, logits, targets, sums);

    final_kernel<<<1, 1, 0, stream>>>(sums, out);
}